// Round 1
// baseline (150.875 us; speedup 1.0000x reference)
//
#include <hip/hip_runtime.h>
#include <stdint.h>

// DecisionTree: out = sum_l p_l * (x @ W_l^T + b_l), p from bottom-layer sigmoids.
// Pair-folded: out = x@Wsum^T + bsum + sum_j p_j*(x@dW_j^T + db_j)  -> 9 GEMMs (bf16 MFMA).

#define M_TOK 4096
#define DDIM  1024
#define NEFF  9

typedef __bf16 bf16x8 __attribute__((ext_vector_type(8)));
typedef float  f32x4  __attribute__((ext_vector_type(4)));
typedef unsigned short u16x4 __attribute__((ext_vector_type(4)));

#define GLB(p) ((const __attribute__((address_space(1))) void*)(p))
#define LDS(p) ((__attribute__((address_space(3))) void*)(p))

__device__ __forceinline__ unsigned short f2bf(float f) {
    union { float f; uint32_t u; } v; v.f = f;
    uint32_t u = v.u;
    return (unsigned short)((u + 0x7fffu + ((u >> 16) & 1u)) >> 16);  // RNE
}

// ---------------- prep: W' (8 deltas + sum) fp32->bf16, bias table ----------------
__global__ __launch_bounds__(256) void prep_w_kernel(
    const float* __restrict__ lw, const float* __restrict__ lb,
    unsigned short* __restrict__ wp, float* __restrict__ bw)
{
    int idx = blockIdx.x * 256 + threadIdx.x;     // 262144 threads: (o, k/4)
    int o  = idx >> 8;
    int k4 = (idx & 255) << 2;
    size_t base = (size_t)o * DDIM + k4;
    float4 acc = make_float4(0.f, 0.f, 0.f, 0.f);
#pragma unroll
    for (int j = 0; j < 8; ++j) {
        const float4 a = *(const float4*)(lw + (size_t)(2*j)   * DDIM*DDIM + base);
        const float4 b = *(const float4*)(lw + (size_t)(2*j+1) * DDIM*DDIM + base);
        u16x4 d;
        d[0] = f2bf(a.x - b.x); d[1] = f2bf(a.y - b.y);
        d[2] = f2bf(a.z - b.z); d[3] = f2bf(a.w - b.w);
        *(u16x4*)(wp + (size_t)j * DDIM*DDIM + base) = d;
        acc.x += b.x; acc.y += b.y; acc.z += b.z; acc.w += b.w;
    }
    u16x4 s;
    s[0] = f2bf(acc.x); s[1] = f2bf(acc.y); s[2] = f2bf(acc.z); s[3] = f2bf(acc.w);
    *(u16x4*)(wp + (size_t)8 * DDIM*DDIM + base) = s;
    if ((idx & 255) == 0) {                       // one thread per o does the biases
        float sb = 0.f;
#pragma unroll
        for (int j = 0; j < 8; ++j) {
            float ba = lb[(2*j) * DDIM + o];
            float bb = lb[(2*j+1) * DDIM + o];
            bw[j * DDIM + o] = ba - bb;
            sb += bb;
        }
        bw[8 * DDIM + o] = sb;
    }
}

// ---------------- dec: per-token wave: 8 sigmoids + x -> bf16 ----------------
__global__ __launch_bounds__(256) void dec_kernel(
    const float* __restrict__ x, const float* __restrict__ dw,
    const float* __restrict__ db, unsigned short* __restrict__ xb,
    float* __restrict__ pmat)
{
    int m    = blockIdx.x * 4 + (threadIdx.x >> 6);
    int lane = threadIdx.x & 63;
    const float* xr = x + (size_t)m * DDIM;
    unsigned short* xo = xb + (size_t)m * DDIM;
    float s[8] = {0.f,0.f,0.f,0.f,0.f,0.f,0.f,0.f};
#pragma unroll
    for (int i = 0; i < 16; ++i) {
        int k = lane + i * 64;
        float v = xr[k];
        xo[k] = f2bf(v);
#pragma unroll
        for (int j = 0; j < 8; ++j)
            s[j] = fmaf(v, dw[(7 + j) * DDIM + k], s[j]);
    }
#pragma unroll
    for (int j = 0; j < 8; ++j)
#pragma unroll
        for (int off = 32; off > 0; off >>= 1)
            s[j] += __shfl_xor(s[j], off);
    if (lane < 8) {
        float t = s[lane] + db[7 + lane];
        pmat[(size_t)m * 8 + lane] = 1.0f / (1.0f + expf(-t));
    }
}

// ---------------- fused 9-leaf GEMM, 128x128 tile, BK=32, m97-style ----------------
__global__ __launch_bounds__(256, 2) void tree_gemm(
    const unsigned short* __restrict__ xb,   // [4096][1024] bf16
    const unsigned short* __restrict__ wp,   // [9][1024][1024] bf16
    const float* __restrict__ bw,            // [9][1024]
    const float* __restrict__ pmat,          // [4096][8]
    float* __restrict__ out,                 // [4096][1024]
    float* __restrict__ parts)               // [2][4096][1024] (ksplit=3 only)
{
    __shared__ __align__(16) unsigned short Asm[2][128 * 32];  // 8KB per buf
    __shared__ __align__(16) unsigned short Bsm[2][128 * 32];
    __shared__ float Psm[128][8];

    const int tid  = threadIdx.x;
    const int lane = tid & 63;
    const int w    = tid >> 6;          // wave 0..3
    const int wm   = w >> 1, wn = w & 1;
    const int bx   = blockIdx.x;        // 0..255
    const int mt   = bx >> 3, nt = bx & 7;
    const int m0   = mt * 128, n0 = nt * 128;
    const int g    = blockIdx.y;
    const int lpg  = NEFF / gridDim.y;  // 3 or 9
    const int leaf0 = g * lpg;
    const int ra   = lane & 15;
    const int kb   = (lane >> 4) * 8;

    // P tile: 128x8 f32 = 4KB
    ((float4*)&Psm[0][0])[tid] = ((const float4*)(pmat + (size_t)m0 * 8))[tid];

    f32x4 acc[4][4]  = {};
    f32x4 oacc[4][4] = {};

    auto stage = [&](int buf, int leaf, int kk) {
#pragma unroll
        for (int c = 0; c < 2; ++c) {
            int row = w * 32 + c * 16 + (lane >> 2);
            int ke  = kk * 32 + (lane & 3) * 8;
            const unsigned short* ga = xb + (size_t)(m0 + row) * DDIM + ke;
            __builtin_amdgcn_global_load_lds(GLB(ga), LDS(&Asm[buf][w * 1024 + c * 512]), 16, 0, 0);
            const unsigned short* gb = wp + (size_t)(leaf * DDIM + n0 + row) * DDIM + ke;
            __builtin_amdgcn_global_load_lds(GLB(gb), LDS(&Bsm[buf][w * 1024 + c * 512]), 16, 0, 0);
        }
    };

    const int TOT = lpg * 32;           // k-steps (K=1024 per leaf, BK=32)
    stage(0, leaf0, 0);
    __syncthreads();
    int cur = 0;
    for (int t = 0; t < TOT; ++t) {
        int nxt = t + 1;
        if (nxt < TOT) stage(cur ^ 1, leaf0 + (nxt >> 5), nxt & 31);

        bf16x8 av[4], bv[4];
#pragma unroll
        for (int i = 0; i < 4; ++i)
            av[i] = *(const bf16x8*)&Asm[cur][(wm * 64 + i * 16 + ra) * 32 + kb];
#pragma unroll
        for (int j = 0; j < 4; ++j)
            bv[j] = *(const bf16x8*)&Bsm[cur][(wn * 64 + j * 16 + ra) * 32 + kb];
#pragma unroll
        for (int i = 0; i < 4; ++i)
#pragma unroll
            for (int j = 0; j < 4; ++j)
                acc[i][j] = __builtin_amdgcn_mfma_f32_16x16x32_bf16(av[i], bv[j], acc[i][j], 0, 0, 0);

        if ((t & 31) == 31) {           // leaf boundary: oacc += p * (acc + bias)
            int leaf = leaf0 + (t >> 5);
            float bb[4];
#pragma unroll
            for (int j = 0; j < 4; ++j)
                bb[j] = bw[leaf * DDIM + n0 + wn * 64 + j * 16 + ra];
#pragma unroll
            for (int i = 0; i < 4; ++i) {
                int rbase = wm * 64 + i * 16 + (lane >> 4) * 4;
#pragma unroll
                for (int r = 0; r < 4; ++r) {
                    float pv = (leaf < 8) ? Psm[rbase + r][leaf] : 1.0f;
#pragma unroll
                    for (int j = 0; j < 4; ++j) {
                        oacc[i][j][r] += pv * (acc[i][j][r] + bb[j]);
                        acc[i][j][r] = 0.f;
                    }
                }
            }
        }
        __syncthreads();
        cur ^= 1;
    }

    float* dst = (g == 0) ? out : parts + (size_t)(g - 1) * M_TOK * DDIM;
#pragma unroll
    for (int i = 0; i < 4; ++i)
#pragma unroll
        for (int r = 0; r < 4; ++r) {
            int row = m0 + wm * 64 + i * 16 + (lane >> 4) * 4 + r;
#pragma unroll
            for (int j = 0; j < 4; ++j) {
                int col = n0 + wn * 64 + j * 16 + ra;
                dst[(size_t)row * DDIM + col] = oacc[i][j][r];
            }
        }
}

// ---------------- reduce: out += parts[0] + parts[1] ----------------
__global__ __launch_bounds__(256) void reduce_kernel(
    float* __restrict__ out, const float* __restrict__ parts)
{
    size_t i = (size_t)blockIdx.x * 256 + threadIdx.x;   // float4 index, 1M total
    float4 a = ((const float4*)out)[i];
    float4 b = ((const float4*)parts)[i];
    float4 c = ((const float4*)(parts + (size_t)M_TOK * DDIM))[i];
    float4 r;
    r.x = a.x + b.x + c.x; r.y = a.y + b.y + c.y;
    r.z = a.z + b.z + c.z; r.w = a.w + b.w + c.w;
    ((float4*)out)[i] = r;
}

extern "C" void kernel_launch(void* const* d_in, const int* in_sizes, int n_in,
                              void* d_out, int out_size, void* d_ws, size_t ws_size,
                              hipStream_t stream) {
    (void)in_sizes; (void)n_in; (void)out_size;
    const float* x     = (const float*)d_in[0];
    const float* dec_w = (const float*)d_in[1];
    const float* dec_b = (const float*)d_in[2];
    const float* lw    = (const float*)d_in[3];
    const float* lb    = (const float*)d_in[4];
    float* out = (float*)d_out;

    uint8_t* w8 = (uint8_t*)d_ws;
    unsigned short* xb   = (unsigned short*)(w8);              //  8 MiB bf16 x
    unsigned short* wp   = (unsigned short*)(w8 + 8388608);    // 18 MiB bf16 W'
    float*          bw   = (float*)(w8 + 27262976);            // 36 KiB biases
    float*          pmat = (float*)(w8 + 27299840);            // 128 KiB probs
    float*          parts= (float*)(w8 + 27430912);            // 32 MiB partials
    const size_t NEED1 = 27430912;
    const size_t NEED3 = 60985344;
    if (ws_size < NEED1) return;  // workspace too small; fail visibly

    prep_w_kernel<<<1024, 256, 0, stream>>>(lw, lb, wp, bw);
    dec_kernel<<<1024, 256, 0, stream>>>(x, dec_w, dec_b, xb, pmat);
    int ngroups = (ws_size >= NEED3) ? 3 : 1;
    tree_gemm<<<dim3(256, ngroups), 256, 0, stream>>>(xb, wp, bw, pmat, out, parts);
    if (ngroups == 3)
        reduce_kernel<<<4096, 256, 0, stream>>>(out, parts);
}